// Round 1
// baseline (763.747 us; speedup 1.0000x reference)
//
#include <hip/hip_runtime.h>
#include <cstdint>
#include <cstddef>

#define Nn 40000
#define Ne 640000
#define CC 128
#define EPSbn 1e-5f

// ---------------- zero ----------------
__global__ void zero_k(int* __restrict__ p, int n){
  int i = blockIdx.x*blockDim.x + threadIdx.x;
  if (i < n) p[i] = 0;
}

// ---------------- generic SGEMM: C = act(A' @ W^T + bias + res') ----------------
// A:[M,K], W:[Ncols,K], C:[M,Ncols]. AFFA: A'[m][k]=A[m][k]*sc[k]+sh[k].
// AFFRES: res'[m][c]=res[m][c]*sc[c]+sh[c].
template<bool HASBIAS,bool HASRES,bool RELU,bool AFFA,bool AFFRES>
__global__ __launch_bounds__(256) void gemm_k(
    const float* __restrict__ A, const float* __restrict__ W,
    const float* __restrict__ bias, const float* __restrict__ res,
    const float* __restrict__ sc, const float* __restrict__ sh,
    float* __restrict__ C, int M, int Ncols, int K)
{
  __shared__ float As[32][68];
  __shared__ float Ws[32][68];
  const int tid = threadIdx.x;
  const int tx = tid & 15, ty = tid >> 4;
  const int row0 = blockIdx.x * 64;
  const int col0 = blockIdx.y * 64;
  float acc[4][4] = {};
  for (int kt = 0; kt < K; kt += 32) {
    #pragma unroll
    for (int l = 0; l < 2; ++l) {
      int idx = tid + l*256;      // 0..511
      int r   = idx >> 3;         // 0..63
      int kq  = (idx & 7) << 2;   // 0,4,..,28
      float4 a4 = *(const float4*)(A + (size_t)(row0 + r)*K + kt + kq);
      if (AFFA) {
        int kk = kt + kq;
        a4.x = a4.x*sc[kk  ] + sh[kk  ];
        a4.y = a4.y*sc[kk+1] + sh[kk+1];
        a4.z = a4.z*sc[kk+2] + sh[kk+2];
        a4.w = a4.w*sc[kk+3] + sh[kk+3];
      }
      As[kq  ][r] = a4.x; As[kq+1][r] = a4.y; As[kq+2][r] = a4.z; As[kq+3][r] = a4.w;
      float4 w4 = *(const float4*)(W + (size_t)(col0 + r)*K + kt + kq);
      Ws[kq  ][r] = w4.x; Ws[kq+1][r] = w4.y; Ws[kq+2][r] = w4.z; Ws[kq+3][r] = w4.w;
    }
    __syncthreads();
    #pragma unroll
    for (int k = 0; k < 32; ++k) {
      float4 av = *(const float4*)&As[k][ty*4];
      float4 bv = *(const float4*)&Ws[k][tx*4];
      float a[4] = {av.x, av.y, av.z, av.w};
      float b[4] = {bv.x, bv.y, bv.z, bv.w};
      #pragma unroll
      for (int i = 0; i < 4; ++i)
        #pragma unroll
        for (int j = 0; j < 4; ++j)
          acc[i][j] += a[i]*b[j];
    }
    __syncthreads();
  }
  const int cb = col0 + tx*4;
  #pragma unroll
  for (int i = 0; i < 4; ++i) {
    int r = row0 + ty*4 + i;
    float o[4] = {acc[i][0], acc[i][1], acc[i][2], acc[i][3]};
    if (HASBIAS) {
      o[0] += bias[cb]; o[1] += bias[cb+1]; o[2] += bias[cb+2]; o[3] += bias[cb+3];
    }
    if (HASRES) {
      float4 rv = *(const float4*)(res + (size_t)r*Ncols + cb);
      float rr[4] = {rv.x, rv.y, rv.z, rv.w};
      if (AFFRES) {
        rr[0] = rr[0]*sc[cb  ] + sh[cb  ];
        rr[1] = rr[1]*sc[cb+1] + sh[cb+1];
        rr[2] = rr[2]*sc[cb+2] + sh[cb+2];
        rr[3] = rr[3]*sc[cb+3] + sh[cb+3];
      }
      o[0] += rr[0]; o[1] += rr[1]; o[2] += rr[2]; o[3] += rr[3];
    }
    if (RELU) {
      o[0] = fmaxf(o[0], 0.f); o[1] = fmaxf(o[1], 0.f);
      o[2] = fmaxf(o[2], 0.f); o[3] = fmaxf(o[3], 0.f);
    }
    float4 ov; ov.x=o[0]; ov.y=o[1]; ov.z=o[2]; ov.w=o[3];
    *(float4*)(C + (size_t)r*Ncols + cb) = ov;
  }
}

// ---------------- per-edge scores ----------------
// scores[e][h] = dot(QD[dst[e]][h*16..], KS[src[e]][h*16..])/4 + dot(ef[e],We[h]) + be[h]
__global__ __launch_bounds__(256) void scores_k(
    const float* __restrict__ QD, const float* __restrict__ KS,
    const float* __restrict__ ef, const int* __restrict__ src,
    const int* __restrict__ dst, const float* __restrict__ We,
    const float* __restrict__ be, float* __restrict__ scores)
{
  __shared__ float efs[32][68];
  __shared__ float Wes[8][68];
  __shared__ float bes[8];
  int tid = threadIdx.x;
  if (tid < 8) bes[tid] = be[tid];
  for (int i = tid; i < 512; i += 256) Wes[i>>6][i&63] = We[i];
  int e0 = blockIdx.x * 32;
  #pragma unroll
  for (int l = 0; l < 2; ++l) {
    int idx = tid + l*256;          // 0..511
    int r   = idx >> 4;             // 0..31
    int q4  = (idx & 15) << 2;      // 0..60
    float4 t = *(const float4*)(ef + (size_t)(e0 + r)*64 + q4);
    efs[r][q4]=t.x; efs[r][q4+1]=t.y; efs[r][q4+2]=t.z; efs[r][q4+3]=t.w;
  }
  __syncthreads();
  int h = tid & 7, el = tid >> 3;
  int e = e0 + el;
  int s = src[e], d = dst[e];
  const float* qp = QD + (size_t)d*128 + h*16;
  const float* kp = KS + (size_t)s*128 + h*16;
  float qk = 0.f;
  #pragma unroll
  for (int i = 0; i < 16; i += 4) {
    float4 a = *(const float4*)(qp + i);
    float4 b = *(const float4*)(kp + i);
    qk += a.x*b.x + a.y*b.y + a.z*b.z + a.w*b.w;
  }
  float es = 0.f;
  #pragma unroll
  for (int kk = 0; kk < 64; kk += 4) {
    float4 a = *(const float4*)&efs[el][kk];
    float4 b = *(const float4*)&Wes[h][kk];
    es += a.x*b.x + a.y*b.y + a.z*b.z + a.w*b.w;
  }
  scores[(size_t)e*8 + h] = qk*0.25f + es + bes[h];
}

// ---------------- CSR build ----------------
__global__ void hist_k(const int* __restrict__ dst, int* __restrict__ counts, int E){
  int i = blockIdx.x*blockDim.x + threadIdx.x;
  if (i < E) atomicAdd(&counts[dst[i]], 1);
}

__global__ __launch_bounds__(256) void scan1_k(
    const int* __restrict__ counts, int* __restrict__ part,
    int* __restrict__ bsums, int n)
{
  int tid = threadIdx.x;
  int base = blockIdx.x*1024 + tid*4;
  int v0 = (base   < n) ? counts[base  ] : 0;
  int v1 = (base+1 < n) ? counts[base+1] : 0;
  int v2 = (base+2 < n) ? counts[base+2] : 0;
  int v3 = (base+3 < n) ? counts[base+3] : 0;
  int t1 = v0+v1, t2 = t1+v2, t3 = t2+v3;
  int lane = tid & 63, wv = tid >> 6;
  int x = t3;
  #pragma unroll
  for (int off = 1; off < 64; off <<= 1) {
    int y = __shfl_up(x, off);
    if (lane >= off) x += y;
  }
  __shared__ int wt[4];
  if (lane == 63) wt[wv] = x;
  __syncthreads();
  int wbase = 0;
  #pragma unroll
  for (int w = 0; w < 4; ++w) if (w < wv) wbase += wt[w];
  int excl = wbase + x - t3;
  if (base   < n) part[base  ] = excl;
  if (base+1 < n) part[base+1] = excl + v0;
  if (base+2 < n) part[base+2] = excl + t1;
  if (base+3 < n) part[base+3] = excl + t2;
  if (tid == 255) bsums[blockIdx.x] = wbase + x;
}

__global__ void scan2_k(int* bsums, int nb){
  int lane = threadIdx.x;
  int v = (lane < nb) ? bsums[lane] : 0;
  int x = v;
  #pragma unroll
  for (int off = 1; off < 64; off <<= 1) {
    int y = __shfl_up(x, off);
    if (lane >= off) x += y;
  }
  if (lane < nb) bsums[lane] = x - v;   // exclusive
}

__global__ void scan3_k(int* __restrict__ offsets, const int* __restrict__ bsums,
                        int* __restrict__ cursor, int n, int E){
  int i = blockIdx.x*blockDim.x + threadIdx.x;
  if (i < n) {
    int o = offsets[i] + bsums[i >> 10];
    offsets[i] = o;
    cursor[i]  = o;
  }
  if (i == 0) offsets[n] = E;
}

__global__ void scatter_k(const int* __restrict__ dst, int* __restrict__ cursor,
                          int* __restrict__ sorted, int E){
  int i = blockIdx.x*blockDim.x + threadIdx.x;
  if (i < E) {
    int p = atomicAdd(&cursor[dst[i]], 1);
    sorted[p] = i;
  }
}

// ---------------- segment softmax + aggregation (one wave per node) ----------------
__global__ __launch_bounds__(256) void agg_k(
    const float* __restrict__ scores, const float* __restrict__ VS,
    const int* __restrict__ sorted, const int* __restrict__ offsets,
    const int* __restrict__ src, float* __restrict__ agg, int n)
{
  int wv = threadIdx.x >> 6, lane = threadIdx.x & 63;
  int node = blockIdx.x*4 + wv;
  if (node >= n) return;
  int beg = offsets[node], end = offsets[node+1];
  int h0 = lane >> 4;     // head for channel c0 = lane (heads 0..3)
  float acc0 = 0.f, acc1 = 0.f, den0 = 0.f, den1 = 0.f;
  for (int i = beg; i < end; ++i) {
    int e = sorted[i];
    float e0 = __expf(scores[(size_t)e*8 + h0]);      // softmax shift-invariant; |s|<~20 safe
    float e1 = __expf(scores[(size_t)e*8 + 4 + h0]);
    const float* vp = VS + (size_t)src[e]*128;
    acc0 += e0 * vp[lane];
    acc1 += e1 * vp[lane + 64];
    den0 += e0; den1 += e1;
  }
  agg[(size_t)node*128 + lane]      = den0 > 0.f ? acc0/den0 : 0.f;
  agg[(size_t)node*128 + 64 + lane] = den1 > 0.f ? acc1/den1 : 0.f;
}

// ---------------- batch-norm stats / finalize / apply ----------------
__global__ __launch_bounds__(256) void bnstats_k(const float* __restrict__ X,
    float* __restrict__ sum, float* __restrict__ sumsq, int M)
{
  int col  = threadIdx.x & 127;
  int half = threadIdx.x >> 7;
  float s = 0.f, q = 0.f;
  for (int r = blockIdx.x*2 + half; r < M; r += gridDim.x*2) {
    float v = X[(size_t)r*128 + col];
    s += v; q += v*v;
  }
  __shared__ float ls[256], lq[256];
  ls[threadIdx.x] = s; lq[threadIdx.x] = q;
  __syncthreads();
  if (half == 0) {
    atomicAdd(&sum[col],   s + ls[threadIdx.x + 128]);
    atomicAdd(&sumsq[col], q + lq[threadIdx.x + 128]);
  }
}

__global__ void bnfin_k(const float* sum, const float* sq, const float* g,
                        const float* bt, float* scale, float* shift, int M){
  int c = threadIdx.x;
  float mu  = sum[c] / (float)M;
  float var = sq[c] / (float)M - mu*mu;
  float s = g[c] * rsqrtf(var + EPSbn);
  scale[c] = s;
  shift[c] = bt[c] - mu*s;
}

__global__ void bnapply_k(const float* __restrict__ Y, const float* __restrict__ scale,
                          const float* __restrict__ shift, float* __restrict__ out, int total){
  int n4 = total >> 2;
  for (int i = blockIdx.x*blockDim.x + threadIdx.x; i < n4; i += gridDim.x*blockDim.x) {
    float4 vv = ((const float4*)Y)[i];
    int c = (i << 2) & 127;
    vv.x = vv.x*scale[c  ] + shift[c  ];
    vv.y = vv.y*scale[c+1] + shift[c+1];
    vv.z = vv.z*scale[c+2] + shift[c+2];
    vv.w = vv.w*scale[c+3] + shift[c+3];
    ((float4*)out)[i] = vv;
  }
}

extern "C" void kernel_launch(void* const* d_in, const int* in_sizes, int n_in,
                              void* d_out, int out_size, void* d_ws, size_t ws_size,
                              hipStream_t stream) {
  const float* q   = (const float*)d_in[0];
  const float* k   = (const float*)d_in[1];
  const float* v   = (const float*)d_in[2];
  const float* ef  = (const float*)d_in[3];
  const int*   src = (const int*)d_in[4];
  const int*   dst = (const int*)d_in[5];
  const float* Wq  = (const float*)d_in[6];
  const float* Wk  = (const float*)d_in[7];
  const float* Wv  = (const float*)d_in[8];
  const float* We  = (const float*)d_in[9];
  const float* be  = (const float*)d_in[10];
  const float* Wo  = (const float*)d_in[11];
  const float* W1  = (const float*)d_in[12];
  const float* b1  = (const float*)d_in[13];
  const float* W2  = (const float*)d_in[14];
  const float* b2  = (const float*)d_in[15];
  const float* g1  = (const float*)d_in[16];
  const float* bt1 = (const float*)d_in[17];
  const float* g2  = (const float*)d_in[18];
  const float* bt2 = (const float*)d_in[19];
  float* out = (float*)d_out;

  // workspace layout (floats): 4 node-feature buffers + bn scratch + int CSR arrays
  float* ws = (float*)d_ws;
  const size_t NB = (size_t)Nn * CC;            // 5,120,000
  float* QD   = ws;                             // projections -> (dead) -> AGG -> Y
  float* KS   = ws + NB;                        // -> RST
  float* VS   = ws + 2*NB;                      // -> H1 (spans VS+SCRS, N*256)
  float* SCRS = ws + 3*NB;                      // scores [E,8]
  float* AGG = QD;
  float* RST = KS;
  float* H1  = VS;
  float* Y   = QD;
  float* bn = ws + 4*NB;                        // 1024 floats
  float* sum1 = bn;       float* sq1 = bn+128;  float* sc1 = bn+256; float* sh1 = bn+384;
  float* sum2 = bn+512;   float* sq2 = bn+640;  float* sc2 = bn+768; float* sh2 = bn+896;
  int* ib      = (int*)(bn + 1024);
  int* counts  = ib;                            // 40000
  int* offsets = ib + 40000;                    // 40001
  int* cursor  = ib + 80001;                    // 40000
  int* sorted  = ib + 120001;                   // 640000
  int* bsums   = ib + 760001;                   // 64

  // zero counts + bn accumulators (ws is poisoned 0xAA every call)
  zero_k<<<dim3(157), 256, 0, stream>>>(counts, Nn);
  zero_k<<<dim3(4),   256, 0, stream>>>((int*)bn, 1024);

  // projections: QD=q@Wq^T, KS=k@Wk^T, VS=v@Wv^T
  dim3 g128(625, 2);
  gemm_k<false,false,false,false,false><<<g128,256,0,stream>>>(q, Wq, nullptr, nullptr, nullptr, nullptr, QD, Nn, 128, 128);
  gemm_k<false,false,false,false,false><<<g128,256,0,stream>>>(k, Wk, nullptr, nullptr, nullptr, nullptr, KS, Nn, 128, 128);
  gemm_k<false,false,false,false,false><<<g128,256,0,stream>>>(v, Wv, nullptr, nullptr, nullptr, nullptr, VS, Nn, 128, 128);

  // per-edge scores
  scores_k<<<dim3(Ne/32), 256, 0, stream>>>(QD, KS, ef, src, dst, We, be, SCRS);

  // CSR build: hist -> scan -> scatter
  hist_k<<<dim3(2500), 256, 0, stream>>>(dst, counts, Ne);
  scan1_k<<<dim3(40), 256, 0, stream>>>(counts, offsets, bsums, Nn);
  scan2_k<<<dim3(1), 64, 0, stream>>>(bsums, 40);
  scan3_k<<<dim3(157), 256, 0, stream>>>(offsets, bsums, cursor, Nn, Ne);
  scatter_k<<<dim3(2500), 256, 0, stream>>>(dst, cursor, sorted, Ne);

  // segment softmax + aggregation, normalized: AGG[node][c]
  agg_k<<<dim3(Nn/4), 256, 0, stream>>>(SCRS, VS, sorted, offsets, src, AGG, Nn);

  // RST = AGG@Wo^T + q
  gemm_k<false,true,false,false,false><<<g128,256,0,stream>>>(AGG, Wo, nullptr, q, nullptr, nullptr, RST, Nn, 128, 128);

  // BN1 stats -> affine (sc1, sh1)
  bnstats_k<<<dim3(256), 256, 0, stream>>>(RST, sum1, sq1, Nn);
  bnfin_k<<<dim3(1), 128, 0, stream>>>(sum1, sq1, g1, bt1, sc1, sh1, Nn);

  // FFN1: H1 = relu(bn1(RST)@W1^T + b1)   [N,256]
  gemm_k<true,false,true,true,false><<<dim3(625,4),256,0,stream>>>(RST, W1, b1, nullptr, sc1, sh1, H1, Nn, 256, 128);

  // FFN2: Y = H1@W2^T + b2 + bn1(RST)     [N,128]
  gemm_k<true,true,false,false,true><<<dim3(625,2),256,0,stream>>>(H1, W2, b2, RST, sc1, sh1, Y, Nn, 128, 256);

  // BN2 stats -> affine -> output
  bnstats_k<<<dim3(256), 256, 0, stream>>>(Y, sum2, sq2, Nn);
  bnfin_k<<<dim3(1), 128, 0, stream>>>(sum2, sq2, g2, bt2, sc2, sh2, Nn);
  bnapply_k<<<dim3(1024), 256, 0, stream>>>(Y, sc2, sh2, out, Nn*CC);
}

// Round 2
// 672.511 us; speedup vs baseline: 1.1357x; 1.1357x over previous
//
#include <hip/hip_runtime.h>
#include <cstdint>
#include <cstddef>

#define Nn 40000
#define Ne 640000
#define CC 128
#define EPSbn 1e-5f

__device__ inline unsigned short f2bf(float x){
  union { float f; unsigned u; } c; c.f = x;
  unsigned r = c.u + 0x7fffu + ((c.u >> 16) & 1u);
  return (unsigned short)(r >> 16);
}

// ---------------- zero ----------------
__global__ void zero_k(int* __restrict__ p, int n){
  int i = blockIdx.x*blockDim.x + threadIdx.x;
  if (i < n) p[i] = 0;
}

// ---------------- generic SGEMM: C = act(A' @ W^T + bias + res') ----------------
// A:[M,K], W:[Ncols,K], C:[M,Ncols]. AFFA: A'[m][k]=A[m][k]*sc[k]+sh[k].
// AFFRES: res'[m][c]=res[m][c]*sc[c]+sh[c]. OUTB16: C stored as bf16.
template<bool HASBIAS,bool HASRES,bool RELU,bool AFFA,bool AFFRES,bool OUTB16>
__global__ __launch_bounds__(256) void gemm_k(
    const float* __restrict__ A, const float* __restrict__ W,
    const float* __restrict__ bias, const float* __restrict__ res,
    const float* __restrict__ sc, const float* __restrict__ sh,
    float* __restrict__ C, int M, int Ncols, int K)
{
  __shared__ float As[32][68];
  __shared__ float Ws[32][68];
  const int tid = threadIdx.x;
  const int tx = tid & 15, ty = tid >> 4;
  const int row0 = blockIdx.x * 64;
  const int col0 = blockIdx.y * 64;
  float acc[4][4] = {};
  for (int kt = 0; kt < K; kt += 32) {
    #pragma unroll
    for (int l = 0; l < 2; ++l) {
      int idx = tid + l*256;      // 0..511
      int r   = idx >> 3;         // 0..63
      int kq  = (idx & 7) << 2;   // 0,4,..,28
      float4 a4 = *(const float4*)(A + (size_t)(row0 + r)*K + kt + kq);
      if (AFFA) {
        int kk = kt + kq;
        a4.x = a4.x*sc[kk  ] + sh[kk  ];
        a4.y = a4.y*sc[kk+1] + sh[kk+1];
        a4.z = a4.z*sc[kk+2] + sh[kk+2];
        a4.w = a4.w*sc[kk+3] + sh[kk+3];
      }
      As[kq  ][r] = a4.x; As[kq+1][r] = a4.y; As[kq+2][r] = a4.z; As[kq+3][r] = a4.w;
      float4 w4 = *(const float4*)(W + (size_t)(col0 + r)*K + kt + kq);
      Ws[kq  ][r] = w4.x; Ws[kq+1][r] = w4.y; Ws[kq+2][r] = w4.z; Ws[kq+3][r] = w4.w;
    }
    __syncthreads();
    #pragma unroll
    for (int k = 0; k < 32; ++k) {
      float4 av = *(const float4*)&As[k][ty*4];
      float4 bv = *(const float4*)&Ws[k][tx*4];
      float a[4] = {av.x, av.y, av.z, av.w};
      float b[4] = {bv.x, bv.y, bv.z, bv.w};
      #pragma unroll
      for (int i = 0; i < 4; ++i)
        #pragma unroll
        for (int j = 0; j < 4; ++j)
          acc[i][j] += a[i]*b[j];
    }
    __syncthreads();
  }
  const int cb = col0 + tx*4;
  #pragma unroll
  for (int i = 0; i < 4; ++i) {
    int r = row0 + ty*4 + i;
    float o[4] = {acc[i][0], acc[i][1], acc[i][2], acc[i][3]};
    if (HASBIAS) {
      o[0] += bias[cb]; o[1] += bias[cb+1]; o[2] += bias[cb+2]; o[3] += bias[cb+3];
    }
    if (HASRES) {
      float4 rv = *(const float4*)(res + (size_t)r*Ncols + cb);
      float rr[4] = {rv.x, rv.y, rv.z, rv.w};
      if (AFFRES) {
        rr[0] = rr[0]*sc[cb  ] + sh[cb  ];
        rr[1] = rr[1]*sc[cb+1] + sh[cb+1];
        rr[2] = rr[2]*sc[cb+2] + sh[cb+2];
        rr[3] = rr[3]*sc[cb+3] + sh[cb+3];
      }
      o[0] += rr[0]; o[1] += rr[1]; o[2] += rr[2]; o[3] += rr[3];
    }
    if (RELU) {
      o[0] = fmaxf(o[0], 0.f); o[1] = fmaxf(o[1], 0.f);
      o[2] = fmaxf(o[2], 0.f); o[3] = fmaxf(o[3], 0.f);
    }
    if (OUTB16) {
      ushort4 ov;
      ov.x = f2bf(o[0]); ov.y = f2bf(o[1]); ov.z = f2bf(o[2]); ov.w = f2bf(o[3]);
      *(ushort4*)((unsigned short*)C + (size_t)r*Ncols + cb) = ov;
    } else {
      float4 ov; ov.x=o[0]; ov.y=o[1]; ov.z=o[2]; ov.w=o[3];
      *(float4*)(C + (size_t)r*Ncols + cb) = ov;
    }
  }
}

// ---------------- per-edge bias: EB[e][h] = dot(ef[e], We[h]) + be[h] (bf16) ----------------
__global__ __launch_bounds__(256) void ebias_k(
    const float* __restrict__ ef, const float* __restrict__ We,
    const float* __restrict__ be, unsigned short* __restrict__ EB)
{
  __shared__ float efs[32][68];
  __shared__ float Wes[8][68];
  __shared__ float bes[8];
  int tid = threadIdx.x;
  if (tid < 8) bes[tid] = be[tid];
  for (int i = tid; i < 512; i += 256) Wes[i>>6][i&63] = We[i];
  int e0 = blockIdx.x * 32;
  #pragma unroll
  for (int l = 0; l < 2; ++l) {
    int idx = tid + l*256;          // 0..511
    int r   = idx >> 4;             // 0..31
    int q4  = (idx & 15) << 2;      // 0..60
    float4 t = *(const float4*)(ef + (size_t)(e0 + r)*64 + q4);
    efs[r][q4]=t.x; efs[r][q4+1]=t.y; efs[r][q4+2]=t.z; efs[r][q4+3]=t.w;
  }
  __syncthreads();
  int h = tid & 7, el = tid >> 3;
  float es = 0.f;
  #pragma unroll
  for (int kk = 0; kk < 64; kk += 4) {
    float4 a = *(const float4*)&efs[el][kk];
    float4 b = *(const float4*)&Wes[h][kk];
    es += a.x*b.x + a.y*b.y + a.z*b.z + a.w*b.w;
  }
  EB[(size_t)(e0 + el)*8 + h] = f2bf(es + bes[h]);
}

// ---------------- CSR build ----------------
__global__ void hist_k(const int* __restrict__ dst, int* __restrict__ counts, int E){
  int i = blockIdx.x*blockDim.x + threadIdx.x;
  if (i < E) atomicAdd(&counts[dst[i]], 1);
}

__global__ __launch_bounds__(256) void scan1_k(
    const int* __restrict__ counts, int* __restrict__ part,
    int* __restrict__ bsums, int n)
{
  int tid = threadIdx.x;
  int base = blockIdx.x*1024 + tid*4;
  int v0 = (base   < n) ? counts[base  ] : 0;
  int v1 = (base+1 < n) ? counts[base+1] : 0;
  int v2 = (base+2 < n) ? counts[base+2] : 0;
  int v3 = (base+3 < n) ? counts[base+3] : 0;
  int t1 = v0+v1, t2 = t1+v2, t3 = t2+v3;
  int lane = tid & 63, wv = tid >> 6;
  int x = t3;
  #pragma unroll
  for (int off = 1; off < 64; off <<= 1) {
    int y = __shfl_up(x, off);
    if (lane >= off) x += y;
  }
  __shared__ int wt[4];
  if (lane == 63) wt[wv] = x;
  __syncthreads();
  int wbase = 0;
  #pragma unroll
  for (int w = 0; w < 4; ++w) if (w < wv) wbase += wt[w];
  int excl = wbase + x - t3;
  if (base   < n) part[base  ] = excl;
  if (base+1 < n) part[base+1] = excl + v0;
  if (base+2 < n) part[base+2] = excl + t1;
  if (base+3 < n) part[base+3] = excl + t2;
  if (tid == 255) bsums[blockIdx.x] = wbase + x;
}

__global__ void scan2_k(int* bsums, int nb){
  int lane = threadIdx.x;
  int v = (lane < nb) ? bsums[lane] : 0;
  int x = v;
  #pragma unroll
  for (int off = 1; off < 64; off <<= 1) {
    int y = __shfl_up(x, off);
    if (lane >= off) x += y;
  }
  if (lane < nb) bsums[lane] = x - v;   // exclusive
}

__global__ void scan3_k(int* __restrict__ offsets, const int* __restrict__ bsums,
                        int* __restrict__ cursor, int n, int E){
  int i = blockIdx.x*blockDim.x + threadIdx.x;
  if (i < n) {
    int o = offsets[i] + bsums[i >> 10];
    offsets[i] = o;
    cursor[i]  = o;
  }
  if (i == 0) offsets[n] = E;
}

__global__ void scatter_k(const int* __restrict__ dst, int* __restrict__ cursor,
                          int* __restrict__ sorted, int E){
  int i = blockIdx.x*blockDim.x + threadIdx.x;
  if (i < E) {
    int p = atomicAdd(&cursor[dst[i]], 1);
    sorted[p] = i;
  }
}

// ---------------- fused scores + segment softmax + aggregation ----------------
// One wave per dst node. Lane l holds channels {2l, 2l+1}; head h = l>>3 (8 lanes/head).
// QD row kept in regs (pre-scaled by 1/sqrt(D)); per-edge: gather KS row (bf16x2/lane),
// butterfly-reduce 8 lanes -> per-head qk dot; w = exp(qk + EB[e][h]); accumulate w*VS row.
__global__ __launch_bounds__(256) void agg_k(
    const unsigned* __restrict__ QDb, const unsigned* __restrict__ KSb,
    const unsigned* __restrict__ VSb, const unsigned short* __restrict__ EB,
    const int* __restrict__ sorted, const int* __restrict__ offsets,
    const int* __restrict__ src, float* __restrict__ agg, int n)
{
  int wv = threadIdx.x >> 6, lane = threadIdx.x & 63;
  int node = blockIdx.x*4 + wv;
  if (node >= n) return;
  unsigned qt = QDb[(size_t)node*64 + lane];
  float q0 = __uint_as_float(qt << 16) * 0.25f;
  float q1 = __uint_as_float(qt & 0xffff0000u) * 0.25f;
  int beg = offsets[node], end = offsets[node+1];
  int hoff = lane >> 3;
  float acc0 = 0.f, acc1 = 0.f, den = 0.f;
  for (int base = beg; base < end; base += 64) {
    int m = end - base; if (m > 64) m = 64;
    int ee = 0, ss = 0;
    if (lane < m) { ee = sorted[base + lane]; ss = src[ee]; }
    for (int j = 0; j < m; ++j) {
      int e = __shfl(ee, j);
      int s = __shfl(ss, j);
      unsigned kt = KSb[(size_t)s*64 + lane];
      float p = q0*__uint_as_float(kt << 16) + q1*__uint_as_float(kt & 0xffff0000u);
      p += __shfl_xor(p, 1);
      p += __shfl_xor(p, 2);
      p += __shfl_xor(p, 4);
      float eb = __uint_as_float(((unsigned)EB[(size_t)e*8 + hoff]) << 16);
      float w = __expf(p + eb);            // softmax shift-invariant; |s| < ~10 safe in fp32
      unsigned vt = VSb[(size_t)s*64 + lane];
      acc0 += w*__uint_as_float(vt << 16);
      acc1 += w*__uint_as_float(vt & 0xffff0000u);
      den += w;
    }
  }
  float inv = den > 0.f ? 1.f/den : 0.f;
  float2 o; o.x = acc0*inv; o.y = acc1*inv;
  *(float2*)(agg + (size_t)node*128 + 2*lane) = o;
}

// ---------------- batch-norm stats / finalize / apply ----------------
__global__ __launch_bounds__(256) void bnstats_k(const float* __restrict__ X,
    float* __restrict__ sum, float* __restrict__ sumsq, int M)
{
  int col  = threadIdx.x & 127;
  int half = threadIdx.x >> 7;
  float s = 0.f, q = 0.f;
  for (int r = blockIdx.x*2 + half; r < M; r += gridDim.x*2) {
    float v = X[(size_t)r*128 + col];
    s += v; q += v*v;
  }
  __shared__ float ls[256], lq[256];
  ls[threadIdx.x] = s; lq[threadIdx.x] = q;
  __syncthreads();
  if (half == 0) {
    atomicAdd(&sum[col],   s + ls[threadIdx.x + 128]);
    atomicAdd(&sumsq[col], q + lq[threadIdx.x + 128]);
  }
}

__global__ void bnfin_k(const float* sum, const float* sq, const float* g,
                        const float* bt, float* scale, float* shift, int M){
  int c = threadIdx.x;
  float mu  = sum[c] / (float)M;
  float var = sq[c] / (float)M - mu*mu;
  float s = g[c] * rsqrtf(var + EPSbn);
  scale[c] = s;
  shift[c] = bt[c] - mu*s;
}

__global__ void bnapply_k(const float* __restrict__ Y, const float* __restrict__ scale,
                          const float* __restrict__ shift, float* __restrict__ out, int total){
  int n4 = total >> 2;
  for (int i = blockIdx.x*blockDim.x + threadIdx.x; i < n4; i += gridDim.x*blockDim.x) {
    float4 vv = ((const float4*)Y)[i];
    int c = (i << 2) & 127;
    vv.x = vv.x*scale[c  ] + shift[c  ];
    vv.y = vv.y*scale[c+1] + shift[c+1];
    vv.z = vv.z*scale[c+2] + shift[c+2];
    vv.w = vv.w*scale[c+3] + shift[c+3];
    ((float4*)out)[i] = vv;
  }
}

extern "C" void kernel_launch(void* const* d_in, const int* in_sizes, int n_in,
                              void* d_out, int out_size, void* d_ws, size_t ws_size,
                              hipStream_t stream) {
  const float* q   = (const float*)d_in[0];
  const float* k   = (const float*)d_in[1];
  const float* v   = (const float*)d_in[2];
  const float* ef  = (const float*)d_in[3];
  const int*   src = (const int*)d_in[4];
  const int*   dst = (const int*)d_in[5];
  const float* Wq  = (const float*)d_in[6];
  const float* Wk  = (const float*)d_in[7];
  const float* Wv  = (const float*)d_in[8];
  const float* We  = (const float*)d_in[9];
  const float* be  = (const float*)d_in[10];
  const float* Wo  = (const float*)d_in[11];
  const float* W1  = (const float*)d_in[12];
  const float* b1  = (const float*)d_in[13];
  const float* W2  = (const float*)d_in[14];
  const float* b2  = (const float*)d_in[15];
  const float* g1  = (const float*)d_in[16];
  const float* bt1 = (const float*)d_in[17];
  const float* g2  = (const float*)d_in[18];
  const float* bt2 = (const float*)d_in[19];
  float* out = (float*)d_out;

  // ---- workspace layout (float units); NB = N*128 = 5.12M ----
  // [0,       NB/2)  QDb  bf16 [N,128]      } overlaid later by H1 [N,256] f32
  // [NB/2,    NB)    KSb  bf16 [N,128]      }
  // [NB,      3NB/2) VSb  bf16 [N,128]      }
  // [3NB/2,   2NB)   EB   bf16 [E,8]        }
  // [2NB,     3NB)   AGG  f32  [N,128]  -> later Y f32 [N,128]
  // [3NB,     4NB)   RST  f32  [N,128]
  // [4NB, +1024)     bn scratch
  // then ints: counts/offsets/cursor/sorted/bsums
  float* ws = (float*)d_ws;
  const size_t NB = (size_t)Nn * CC;            // 5,120,000
  float* QDb = ws;                               // bf16 (as uint-packed)
  float* KSb = ws + NB/2;
  float* VSb = ws + NB;
  unsigned short* EBb = (unsigned short*)(ws + 3*NB/2);
  float* AGG = ws + 2*NB;
  float* RST = ws + 3*NB;
  float* H1  = ws;                               // [N,256] f32, overlays QDb..EB (dead)
  float* Y   = AGG;                              // overlays AGG (dead after Wo gemm)
  float* bn = ws + 4*NB;                         // 1024 floats
  float* sum1 = bn;       float* sq1 = bn+128;  float* sc1 = bn+256; float* sh1 = bn+384;
  float* sum2 = bn+512;   float* sq2 = bn+640;  float* sc2 = bn+768; float* sh2 = bn+896;
  int* ib      = (int*)(bn + 1024);
  int* counts  = ib;                            // 40000
  int* offsets = ib + 40000;                    // 40001
  int* cursor  = ib + 80001;                    // 40000
  int* sorted  = ib + 120001;                   // 640000
  int* bsums   = ib + 760001;                   // 64

  // zero counts + bn accumulators (ws is poisoned 0xAA every call)
  zero_k<<<dim3(157), 256, 0, stream>>>(counts, Nn);
  zero_k<<<dim3(4),   256, 0, stream>>>((int*)bn, 1024);

  // projections -> bf16 tables: QDb=q@Wq^T, KSb=k@Wk^T, VSb=v@Wv^T
  dim3 g128(625, 2);
  gemm_k<false,false,false,false,false,true><<<g128,256,0,stream>>>(q, Wq, nullptr, nullptr, nullptr, nullptr, QDb, Nn, 128, 128);
  gemm_k<false,false,false,false,false,true><<<g128,256,0,stream>>>(k, Wk, nullptr, nullptr, nullptr, nullptr, KSb, Nn, 128, 128);
  gemm_k<false,false,false,false,false,true><<<g128,256,0,stream>>>(v, Wv, nullptr, nullptr, nullptr, nullptr, VSb, Nn, 128, 128);

  // per-edge bias (streaming, compulsory 164 MB read)
  ebias_k<<<dim3(Ne/32), 256, 0, stream>>>(ef, We, be, EBb);

  // CSR build: hist -> scan -> scatter
  hist_k<<<dim3(2500), 256, 0, stream>>>(dst, counts, Ne);
  scan1_k<<<dim3(40), 256, 0, stream>>>(counts, offsets, bsums, Nn);
  scan2_k<<<dim3(1), 64, 0, stream>>>(bsums, 40);
  scan3_k<<<dim3(157), 256, 0, stream>>>(offsets, bsums, cursor, Nn, Ne);
  scatter_k<<<dim3(2500), 256, 0, stream>>>(dst, cursor, sorted, Ne);

  // fused scores + segment softmax + aggregation
  agg_k<<<dim3(Nn/4), 256, 0, stream>>>((const unsigned*)QDb, (const unsigned*)KSb,
                                        (const unsigned*)VSb, EBb,
                                        sorted, offsets, src, AGG, Nn);

  // RST = AGG@Wo^T + q
  gemm_k<false,true,false,false,false,false><<<g128,256,0,stream>>>(AGG, Wo, nullptr, q, nullptr, nullptr, RST, Nn, 128, 128);

  // BN1 stats -> affine (sc1, sh1)
  bnstats_k<<<dim3(256), 256, 0, stream>>>(RST, sum1, sq1, Nn);
  bnfin_k<<<dim3(1), 128, 0, stream>>>(sum1, sq1, g1, bt1, sc1, sh1, Nn);

  // FFN1: H1 = relu(bn1(RST)@W1^T + b1)   [N,256]
  gemm_k<true,false,true,true,false,false><<<dim3(625,4),256,0,stream>>>(RST, W1, b1, nullptr, sc1, sh1, H1, Nn, 256, 128);

  // FFN2: Y = H1@W2^T + b2 + bn1(RST)     [N,128]
  gemm_k<true,true,false,false,true,false><<<dim3(625,2),256,0,stream>>>(H1, W2, b2, RST, sc1, sh1, Y, Nn, 128, 256);

  // BN2 stats -> affine -> output
  bnstats_k<<<dim3(256), 256, 0, stream>>>(Y, sum2, sq2, Nn);
  bnfin_k<<<dim3(1), 128, 0, stream>>>(sum2, sq2, g2, bt2, sc2, sh2, Nn);
  bnapply_k<<<dim3(1024), 256, 0, stream>>>(Y, sc2, sh2, out, Nn*CC);
}

// Round 3
// 571.643 us; speedup vs baseline: 1.3361x; 1.1765x over previous
//
#include <hip/hip_runtime.h>
#include <cstdint>
#include <cstddef>

#define Nn 40000
#define Ne 640000
#define CC 128
#define EPSbn 1e-5f

typedef __attribute__((ext_vector_type(8))) __bf16 bf16x8;
typedef __attribute__((ext_vector_type(4))) float floatx4;

__device__ inline unsigned short f2bf(float x){
  union { float f; unsigned u; } c; c.f = x;
  unsigned r = c.u + 0x7fffu + ((c.u >> 16) & 1u);
  return (unsigned short)(r >> 16);
}
__device__ inline float bflo(unsigned u){ return __uint_as_float(u << 16); }
__device__ inline float bfhi(unsigned u){ return __uint_as_float(u & 0xffff0000u); }

// ---------------- zero ----------------
__global__ void zero_k(int* __restrict__ p, int n){
  int i = blockIdx.x*blockDim.x + threadIdx.x;
  if (i < n) p[i] = 0;
}

// ---------------- MFMA bf16 GEMM: C = act(A' @ W^T + bias + res') ----------------
// A:[M,K] (fp32 or bf16 per ABF16), W:[*,K] fp32, C:[M,Ncols].
// Tile 128x128, block=256 (4 waves), wave computes 32 rows x 128 cols.
// AFFA: A'[m][k]=A[m][k]*sc[k]+sh[k].  AFFRES: res'[m][c]=res[m][c]*sc[c]+sh[c].
template<int KTILES,bool ABF16,bool HASBIAS,bool HASRES,bool RELU,bool AFFA,bool AFFRES,bool OUTB16>
__global__ __launch_bounds__(256,2) void mgemm_k(
    const void* __restrict__ Ap, const float* __restrict__ W,
    const float* __restrict__ bias, const float* __restrict__ res,
    const float* __restrict__ sc, const float* __restrict__ sh,
    void* __restrict__ Cp, int M, int Ncols)
{
  constexpr int K = KTILES * 128;
  __shared__ __align__(16) unsigned short As[128*136];  // +8 pad: 2-way bank alias (free)
  __shared__ __align__(16) unsigned short Ws[128*136];
  const int tid  = threadIdx.x;
  const int lane = tid & 63;
  const int wv   = tid >> 6;
  const int m    = lane & 15;
  const int quad = lane >> 4;
  const int row0 = blockIdx.x * 128;
  const int col0 = blockIdx.y * 128;
  floatx4 acc[2][8] = {};

  for (int kt = 0; kt < K; kt += 128) {
    #pragma unroll 4
    for (int it = 0; it < 16; ++it) {
      int s = tid + it*256;        // 0..4095
      int r = s >> 5;              // 0..127
      int c = (s & 31) << 2;       // 0..124
      int gr = row0 + r; if (gr >= M) gr = M - 1;
      ushort4 ua;
      if (ABF16) {
        ua = *(const ushort4*)((const unsigned short*)Ap + (size_t)gr*K + kt + c);
      } else {
        float4 a4 = *(const float4*)((const float*)Ap + (size_t)gr*K + kt + c);
        if (AFFA) {
          int kk = kt + c;
          a4.x = a4.x*sc[kk  ] + sh[kk  ];
          a4.y = a4.y*sc[kk+1] + sh[kk+1];
          a4.z = a4.z*sc[kk+2] + sh[kk+2];
          a4.w = a4.w*sc[kk+3] + sh[kk+3];
        }
        ua.x = f2bf(a4.x); ua.y = f2bf(a4.y); ua.z = f2bf(a4.z); ua.w = f2bf(a4.w);
      }
      *(ushort4*)&As[r*136 + c] = ua;
      float4 w4 = *(const float4*)(W + (size_t)(col0 + r)*K + kt + c);
      ushort4 uw;
      uw.x = f2bf(w4.x); uw.y = f2bf(w4.y); uw.z = f2bf(w4.z); uw.w = f2bf(w4.w);
      *(ushort4*)&Ws[r*136 + c] = uw;
    }
    __syncthreads();
    #pragma unroll
    for (int ks = 0; ks < 4; ++ks) {
      int ko = ks*32 + quad*8;
      bf16x8 a0 = *(const bf16x8*)&As[(32*wv      + m)*136 + ko];
      bf16x8 a1 = *(const bf16x8*)&As[(32*wv + 16 + m)*136 + ko];
      #pragma unroll
      for (int j = 0; j < 8; ++j) {
        bf16x8 bj = *(const bf16x8*)&Ws[(16*j + m)*136 + ko];
        acc[0][j] = __builtin_amdgcn_mfma_f32_16x16x32_bf16(a0, bj, acc[0][j], 0, 0, 0);
        acc[1][j] = __builtin_amdgcn_mfma_f32_16x16x32_bf16(a1, bj, acc[1][j], 0, 0, 0);
      }
    }
    __syncthreads();
  }

  float bcol[8], scv[8], shv[8];
  #pragma unroll
  for (int j = 0; j < 8; ++j) {
    int gcol = col0 + 16*j + m;
    if (HASBIAS) bcol[j] = bias[gcol];
    if (AFFRES) { scv[j] = sc[gcol]; shv[j] = sh[gcol]; }
  }
  #pragma unroll
  for (int rt = 0; rt < 2; ++rt) {
    #pragma unroll
    for (int rg = 0; rg < 4; ++rg) {
      int grow = row0 + 32*wv + 16*rt + quad*4 + rg;
      if (grow < M) {
        #pragma unroll
        for (int j = 0; j < 8; ++j) {
          int gcol = col0 + 16*j + m;
          float o = acc[rt][j][rg];
          if (HASBIAS) o += bcol[j];
          if (HASRES) {
            float rr = res[(size_t)grow*Ncols + gcol];
            if (AFFRES) rr = rr*scv[j] + shv[j];
            o += rr;
          }
          if (RELU) o = fmaxf(o, 0.f);
          if (OUTB16) ((unsigned short*)Cp)[(size_t)grow*Ncols + gcol] = f2bf(o);
          else        ((float*)Cp)[(size_t)grow*Ncols + gcol] = o;
        }
      }
    }
  }
}

// ---------------- per-edge bias -> CSR-ordered bf16 table ----------------
// EBs[pos[e]][h] = dot(ef[e], We[h]) + be[h]
__global__ __launch_bounds__(256) void ebias_k(
    const float* __restrict__ ef, const float* __restrict__ We,
    const float* __restrict__ be, const int* __restrict__ pos,
    unsigned short* __restrict__ EBs)
{
  __shared__ float efs[32][68];
  __shared__ float Wes[8][68];
  __shared__ float bes[8];
  int tid = threadIdx.x;
  if (tid < 8) bes[tid] = be[tid];
  for (int i = tid; i < 512; i += 256) Wes[i>>6][i&63] = We[i];
  int e0 = blockIdx.x * 32;
  #pragma unroll
  for (int l = 0; l < 2; ++l) {
    int idx = tid + l*256;
    int r   = idx >> 4;
    int q4  = (idx & 15) << 2;
    float4 t = *(const float4*)(ef + (size_t)(e0 + r)*64 + q4);
    efs[r][q4]=t.x; efs[r][q4+1]=t.y; efs[r][q4+2]=t.z; efs[r][q4+3]=t.w;
  }
  __syncthreads();
  int h = tid & 7, el = tid >> 3;
  int e = e0 + el;
  float es = 0.f;
  #pragma unroll
  for (int kk = 0; kk < 64; kk += 4) {
    float4 a = *(const float4*)&efs[el][kk];
    float4 b = *(const float4*)&Wes[h][kk];
    es += a.x*b.x + a.y*b.y + a.z*b.z + a.w*b.w;
  }
  EBs[(size_t)pos[e]*8 + h] = f2bf(es + bes[h]);
}

// ---------------- CSR build ----------------
__global__ void hist_k(const int* __restrict__ dst, int* __restrict__ counts, int E){
  int i = blockIdx.x*blockDim.x + threadIdx.x;
  if (i < E) atomicAdd(&counts[dst[i]], 1);
}

__global__ __launch_bounds__(256) void scan1_k(
    const int* __restrict__ counts, int* __restrict__ part,
    int* __restrict__ bsums, int n)
{
  int tid = threadIdx.x;
  int base = blockIdx.x*1024 + tid*4;
  int v0 = (base   < n) ? counts[base  ] : 0;
  int v1 = (base+1 < n) ? counts[base+1] : 0;
  int v2 = (base+2 < n) ? counts[base+2] : 0;
  int v3 = (base+3 < n) ? counts[base+3] : 0;
  int t1 = v0+v1, t2 = t1+v2, t3 = t2+v3;
  int lane = tid & 63, wv = tid >> 6;
  int x = t3;
  #pragma unroll
  for (int off = 1; off < 64; off <<= 1) {
    int y = __shfl_up(x, off);
    if (lane >= off) x += y;
  }
  __shared__ int wt[4];
  if (lane == 63) wt[wv] = x;
  __syncthreads();
  int wbase = 0;
  #pragma unroll
  for (int w = 0; w < 4; ++w) if (w < wv) wbase += wt[w];
  int excl = wbase + x - t3;
  if (base   < n) part[base  ] = excl;
  if (base+1 < n) part[base+1] = excl + v0;
  if (base+2 < n) part[base+2] = excl + t1;
  if (base+3 < n) part[base+3] = excl + t2;
  if (tid == 255) bsums[blockIdx.x] = wbase + x;
}

__global__ void scan2_k(int* bsums, int nb){
  int lane = threadIdx.x;
  int v = (lane < nb) ? bsums[lane] : 0;
  int x = v;
  #pragma unroll
  for (int off = 1; off < 64; off <<= 1) {
    int y = __shfl_up(x, off);
    if (lane >= off) x += y;
  }
  if (lane < nb) bsums[lane] = x - v;   // exclusive
}

__global__ void scan3_k(int* __restrict__ offsets, const int* __restrict__ bsums,
                        int* __restrict__ cursor, int n, int E){
  int i = blockIdx.x*blockDim.x + threadIdx.x;
  if (i < n) {
    int o = offsets[i] + bsums[i >> 10];
    offsets[i] = o;
    cursor[i]  = o;
  }
  if (i == 0) offsets[n] = E;
}

// scatter: compute CSR position, emit inverse perm (pos) and src gathered by position
__global__ void scatter_k(const int* __restrict__ dst, const int* __restrict__ src,
                          int* __restrict__ cursor, int* __restrict__ pos,
                          int* __restrict__ srcs, int E){
  int i = blockIdx.x*blockDim.x + threadIdx.x;
  if (i < E) {
    int p = atomicAdd(&cursor[dst[i]], 1);
    pos[i]  = p;
    srcs[p] = src[i];
  }
}

// ---------------- fused scores + segment softmax + aggregation ----------------
// One wave per dst node; lane l holds channels {2l,2l+1}; head = l>>3.
__global__ __launch_bounds__(256) void agg_k(
    const unsigned* __restrict__ QDb, const unsigned* __restrict__ KSb,
    const unsigned* __restrict__ VSb, const unsigned short* __restrict__ EBs,
    const int* __restrict__ offsets, const int* __restrict__ srcs,
    float* __restrict__ agg, int n)
{
  int wv = threadIdx.x >> 6, lane = threadIdx.x & 63;
  int node = blockIdx.x*4 + wv;
  if (node >= n) return;
  unsigned qt = QDb[(size_t)node*64 + lane];
  float q0 = bflo(qt) * 0.25f;
  float q1 = bfhi(qt) * 0.25f;
  int beg = offsets[node], end = offsets[node+1];
  int hoff = lane >> 3;
  float acc0 = 0.f, acc1 = 0.f, den = 0.f;
  for (int base = beg; base < end; base += 64) {
    int mrem = end - base; if (mrem > 64) mrem = 64;
    int ss = (lane < mrem) ? srcs[base + lane] : 0;
    int j = 0;
    for (; j + 2 <= mrem; j += 2) {
      int s0 = __shfl(ss, j);
      int s1 = __shfl(ss, j+1);
      unsigned kt0 = KSb[(size_t)s0*64 + lane];
      unsigned kt1 = KSb[(size_t)s1*64 + lane];
      unsigned vt0 = VSb[(size_t)s0*64 + lane];
      unsigned vt1 = VSb[(size_t)s1*64 + lane];
      float p0 = q0*bflo(kt0) + q1*bfhi(kt0);
      float p1 = q0*bflo(kt1) + q1*bfhi(kt1);
      p0 += __shfl_xor(p0, 1);  p1 += __shfl_xor(p1, 1);
      p0 += __shfl_xor(p0, 2);  p1 += __shfl_xor(p1, 2);
      p0 += __shfl_xor(p0, 4);  p1 += __shfl_xor(p1, 4);
      float eb0 = bflo((unsigned)EBs[(size_t)(base+j  )*8 + hoff] << 16 >> 16 << 16);
      float eb1 = bflo((unsigned)EBs[(size_t)(base+j+1)*8 + hoff] << 16 >> 16 << 16);
      eb0 = __uint_as_float(((unsigned)EBs[(size_t)(base+j  )*8 + hoff]) << 16);
      eb1 = __uint_as_float(((unsigned)EBs[(size_t)(base+j+1)*8 + hoff]) << 16);
      float w0 = __expf(p0 + eb0);     // softmax shift-invariant; fp32 exp safe here
      float w1 = __expf(p1 + eb1);
      acc0 += w0*bflo(vt0) + w1*bflo(vt1);
      acc1 += w0*bfhi(vt0) + w1*bfhi(vt1);
      den  += w0 + w1;
    }
    if (j < mrem) {
      int s0 = __shfl(ss, j);
      unsigned kt0 = KSb[(size_t)s0*64 + lane];
      unsigned vt0 = VSb[(size_t)s0*64 + lane];
      float p0 = q0*bflo(kt0) + q1*bfhi(kt0);
      p0 += __shfl_xor(p0, 1);
      p0 += __shfl_xor(p0, 2);
      p0 += __shfl_xor(p0, 4);
      float eb0 = __uint_as_float(((unsigned)EBs[(size_t)(base+j)*8 + hoff]) << 16);
      float w0 = __expf(p0 + eb0);
      acc0 += w0*bflo(vt0);
      acc1 += w0*bfhi(vt0);
      den  += w0;
    }
  }
  float inv = den > 0.f ? 1.f/den : 0.f;
  float2 o; o.x = acc0*inv; o.y = acc1*inv;
  *(float2*)(agg + (size_t)node*128 + 2*lane) = o;
}

// ---------------- batch-norm stats / finalize / apply ----------------
__global__ __launch_bounds__(256) void bnstats_k(const float* __restrict__ X,
    float* __restrict__ sum, float* __restrict__ sumsq, int M)
{
  int col  = threadIdx.x & 127;
  int half = threadIdx.x >> 7;
  float s = 0.f, q = 0.f;
  for (int r = blockIdx.x*2 + half; r < M; r += gridDim.x*2) {
    float v = X[(size_t)r*128 + col];
    s += v; q += v*v;
  }
  __shared__ float ls[256], lq[256];
  ls[threadIdx.x] = s; lq[threadIdx.x] = q;
  __syncthreads();
  if (half == 0) {
    atomicAdd(&sum[col],   s + ls[threadIdx.x + 128]);
    atomicAdd(&sumsq[col], q + lq[threadIdx.x + 128]);
  }
}

__global__ void bnfin_k(const float* sum, const float* sq, const float* g,
                        const float* bt, float* scale, float* shift, int M){
  int c = threadIdx.x;
  float mu  = sum[c] / (float)M;
  float var = sq[c] / (float)M - mu*mu;
  float s = g[c] * rsqrtf(var + EPSbn);
  scale[c] = s;
  shift[c] = bt[c] - mu*s;
}

__global__ void bnapply_k(const float* __restrict__ Y, const float* __restrict__ scale,
                          const float* __restrict__ shift, float* __restrict__ out, int total){
  int n4 = total >> 2;
  for (int i = blockIdx.x*blockDim.x + threadIdx.x; i < n4; i += gridDim.x*blockDim.x) {
    float4 vv = ((const float4*)Y)[i];
    int c = (i << 2) & 127;
    vv.x = vv.x*scale[c  ] + shift[c  ];
    vv.y = vv.y*scale[c+1] + shift[c+1];
    vv.z = vv.z*scale[c+2] + shift[c+2];
    vv.w = vv.w*scale[c+3] + shift[c+3];
    ((float4*)out)[i] = vv;
  }
}

extern "C" void kernel_launch(void* const* d_in, const int* in_sizes, int n_in,
                              void* d_out, int out_size, void* d_ws, size_t ws_size,
                              hipStream_t stream) {
  const float* q   = (const float*)d_in[0];
  const float* k   = (const float*)d_in[1];
  const float* v   = (const float*)d_in[2];
  const float* ef  = (const float*)d_in[3];
  const int*   src = (const int*)d_in[4];
  const int*   dst = (const int*)d_in[5];
  const float* Wq  = (const float*)d_in[6];
  const float* Wk  = (const float*)d_in[7];
  const float* Wv  = (const float*)d_in[8];
  const float* We  = (const float*)d_in[9];
  const float* be  = (const float*)d_in[10];
  const float* Wo  = (const float*)d_in[11];
  const float* W1  = (const float*)d_in[12];
  const float* b1  = (const float*)d_in[13];
  const float* W2  = (const float*)d_in[14];
  const float* b2  = (const float*)d_in[15];
  const float* g1  = (const float*)d_in[16];
  const float* bt1 = (const float*)d_in[17];
  const float* g2  = (const float*)d_in[18];
  const float* bt2 = (const float*)d_in[19];
  float* out = (float*)d_out;

  // ---- workspace layout (float units); NB = N*128 = 5.12M ----
  // [0,     NB/2)   QDb bf16 [N,128]   }  H1 bf16 [N,256] overlays [0,NB) later
  // [NB/2,  NB)     KSb bf16 [N,128]   }
  // [NB,    3NB/2)  VSb bf16 [N,128]
  // [3NB/2, 2NB)    EBs bf16 [E,8] (CSR order)
  // [2NB,   3NB)    AGG f32 -> Y f32
  // [3NB,   4NB)    RST f32
  // [4NB, +1024)    bn scratch; ints after
  float* ws = (float*)d_ws;
  const size_t NB = (size_t)Nn * CC;            // 5,120,000
  float* QDb = ws;
  float* KSb = ws + NB/2;
  float* VSb = ws + NB;
  unsigned short* EBs = (unsigned short*)(ws + 3*NB/2);
  float* AGG = ws + 2*NB;
  float* RST = ws + 3*NB;
  float* H1  = ws;          // [N,256] bf16 = NB float-units, overlays QDb+KSb (dead)
  float* Y   = AGG;         // overlays AGG (dead after Wo gemm)
  float* bn = ws + 4*NB;
  float* sum1 = bn;       float* sq1 = bn+128;  float* sc1 = bn+256; float* sh1 = bn+384;
  float* sum2 = bn+512;   float* sq2 = bn+640;  float* sc2 = bn+768; float* sh2 = bn+896;
  int* ib      = (int*)(bn + 1024);
  int* counts  = ib;                    // 40000
  int* offsets = ib + 40000;            // 40001
  int* cursor  = ib + 80001;            // 40000
  int* posA    = ib + 120001;           // 640000
  int* srcsA   = ib + 760001;           // 640000
  int* bsums   = ib + 1400001;          // 64

  zero_k<<<dim3(157), 256, 0, stream>>>(counts, Nn);
  zero_k<<<dim3(4),   256, 0, stream>>>((int*)bn, 1024);

  // CSR build
  hist_k<<<dim3(2500), 256, 0, stream>>>(dst, counts, Ne);
  scan1_k<<<dim3(40), 256, 0, stream>>>(counts, offsets, bsums, Nn);
  scan2_k<<<dim3(1), 64, 0, stream>>>(bsums, 40);
  scan3_k<<<dim3(157), 256, 0, stream>>>(offsets, bsums, cursor, Nn, Ne);
  scatter_k<<<dim3(2500), 256, 0, stream>>>(dst, src, cursor, posA, srcsA, Ne);

  // projections -> bf16 tables
  dim3 g1d(313, 1);
  mgemm_k<1,false,false,false,false,false,false,true><<<g1d,256,0,stream>>>(q, Wq, nullptr, nullptr, nullptr, nullptr, QDb, Nn, 128);
  mgemm_k<1,false,false,false,false,false,false,true><<<g1d,256,0,stream>>>(k, Wk, nullptr, nullptr, nullptr, nullptr, KSb, Nn, 128);
  mgemm_k<1,false,false,false,false,false,false,true><<<g1d,256,0,stream>>>(v, Wv, nullptr, nullptr, nullptr, nullptr, VSb, Nn, 128);

  // per-edge bias, written in CSR order
  ebias_k<<<dim3(Ne/32), 256, 0, stream>>>(ef, We, be, posA, EBs);

  // fused scores + segment softmax + aggregation
  agg_k<<<dim3(Nn/4), 256, 0, stream>>>((const unsigned*)QDb, (const unsigned*)KSb,
                                        (const unsigned*)VSb, EBs,
                                        offsets, srcsA, AGG, Nn);

  // RST = AGG@Wo^T + q
  mgemm_k<1,false,false,true,false,false,false,false><<<g1d,256,0,stream>>>(AGG, Wo, nullptr, q, nullptr, nullptr, RST, Nn, 128);

  // BN1 stats -> affine
  bnstats_k<<<dim3(256), 256, 0, stream>>>(RST, sum1, sq1, Nn);
  bnfin_k<<<dim3(1), 128, 0, stream>>>(sum1, sq1, g1, bt1, sc1, sh1, Nn);

  // FFN1: H1 = relu(bn1(RST)@W1^T + b1)  [N,256] bf16
  mgemm_k<1,false,true,false,true,true,false,true><<<dim3(313,2),256,0,stream>>>(RST, W1, b1, nullptr, sc1, sh1, H1, Nn, 256);

  // FFN2: Y = H1@W2^T + b2 + bn1(RST)    [N,128] f32
  mgemm_k<2,true,true,true,false,false,true,false><<<g1d,256,0,stream>>>(H1, W2, b2, RST, sc1, sh1, Y, Nn, 128);

  // BN2 -> out
  bnstats_k<<<dim3(256), 256, 0, stream>>>(Y, sum2, sq2, Nn);
  bnfin_k<<<dim3(1), 128, 0, stream>>>(sum2, sq2, g2, bt2, sc2, sh2, Nn);
  bnapply_k<<<dim3(1024), 256, 0, stream>>>(Y, sc2, sh2, out, Nn*CC);
}